// Round 1
// baseline (1006.475 us; speedup 1.0000x reference)
//
#include <hip/hip_runtime.h>

// MinkowskiConcat forward:
//   out[n_out, 256] = 0
//   out[map1_out[i], 0:128]   += feat1[map1_in[i]]   (i < N1)
//   out[map2_out[i], 128:256] += feat2[map2_in[i]]   (i < N2)
// f32 everywhere; maps arrive as int32 per harness contract.

constexpr int C_IN  = 128;   // per-input channels
constexpr int C_OUT = 256;   // concat width

__global__ void zero_out_kernel(float4* __restrict__ out, long n4) {
    long i      = (long)blockIdx.x * blockDim.x + threadIdx.x;
    long stride = (long)gridDim.x * blockDim.x;
    const float4 z = {0.f, 0.f, 0.f, 0.f};
    for (; i < n4; i += stride) out[i] = z;
}

// 64 consecutive threads handle one input row; each thread owns 2 floats.
__global__ void scatter_add_kernel(const float* __restrict__ feat,
                                   const int*   __restrict__ map_in,
                                   const int*   __restrict__ map_out,
                                   float*       __restrict__ out,
                                   int n_rows, int col_off) {
    int gid = blockIdx.x * blockDim.x + threadIdx.x;
    int row = gid >> 6;          // one wave64 per input row
    int t   = gid & 63;          // lane within row
    if (row >= n_rows) return;

    int in_row  = map_in[row];
    int out_row = map_out[row];

    const float2 v =
        *reinterpret_cast<const float2*>(feat + (long)in_row * C_IN + t * 2);
    float* dst = out + (long)out_row * C_OUT + col_off + t * 2;

    // hardware global_atomic_add_f32 (coarse-grained device memory)
    unsafeAtomicAdd(dst,     v.x);
    unsafeAtomicAdd(dst + 1, v.y);
}

extern "C" void kernel_launch(void* const* d_in, const int* in_sizes, int n_in,
                              void* d_out, int out_size, void* d_ws, size_t ws_size,
                              hipStream_t stream) {
    const float* feat1    = (const float*)d_in[0];
    const float* feat2    = (const float*)d_in[1];
    const int*   map1_in  = (const int*)d_in[2];
    const int*   map1_out = (const int*)d_in[3];
    const int*   map2_in  = (const int*)d_in[4];
    const int*   map2_out = (const int*)d_in[5];
    float*       out      = (float*)d_out;

    const int n1 = in_sizes[0] / C_IN;   // 524288
    const int n2 = in_sizes[1] / C_IN;   // 524288

    // 1) zero the output (harness poisons d_out before timing)
    {
        long n4 = (long)out_size / 4;
        int threads = 256;
        int blocks  = 2048;   // grid-stride; 256 CUs * 8
        zero_out_kernel<<<blocks, threads, 0, stream>>>((float4*)out, n4);
    }

    // 2) scatter side 1 -> cols [0,128)
    {
        int threads = 256;                 // 4 rows per block
        int blocks  = (n1 + 3) / 4;
        scatter_add_kernel<<<blocks, threads, 0, stream>>>(
            feat1, map1_in, map1_out, out, n1, 0);
    }

    // 3) scatter side 2 -> cols [128,256)
    {
        int threads = 256;
        int blocks  = (n2 + 3) / 4;
        scatter_add_kernel<<<blocks, threads, 0, stream>>>(
            feat2, map2_in, map2_out, out, n2, C_IN);
    }
}

// Round 2
// 583.007 us; speedup vs baseline: 1.7264x; 1.7264x over previous
//
#include <hip/hip_runtime.h>

// MinkowskiConcat forward, CSR-gather formulation:
//   counts[r]  = #inputs mapping to output row r (side1 rows [0,NOUT), side2 [NOUT,2*NOUT))
//   offsets    = exclusive scan(counts), sentinel at [2*NOUT] = n1+n2
//   idxpool[p] = source feat row for segment position p
//   gather: wave per output row, sum segment rows, plain stores (no zero pass, no f32 atomics)

constexpr int C_IN  = 128;
constexpr int C_OUT = 256;
constexpr int SCAN_TPB = 256;
constexpr int SCAN_EPT = 16;                      // elements per thread
constexpr int SCAN_EPB = SCAN_TPB * SCAN_EPT;     // 4096 per block

__global__ void zero_int_kernel(int* __restrict__ p, int n) {
    int i = blockIdx.x * blockDim.x + threadIdx.x;
    int stride = gridDim.x * blockDim.x;
    for (; i < n; i += stride) p[i] = 0;
}

__global__ void count_kernel(const int* __restrict__ m1o, const int* __restrict__ m2o,
                             int* __restrict__ counts, int n1, int n2, int n_out) {
    int i = blockIdx.x * blockDim.x + threadIdx.x;
    int n = n1 + n2;
    if (i >= n) return;
    if (i < n1) atomicAdd(&counts[m1o[i]], 1);
    else        atomicAdd(&counts[n_out + m2o[i - n1]], 1);
}

// K1: per-block sums of counts
__global__ void scan_blocksums_kernel(const int* __restrict__ counts, int nc,
                                      int* __restrict__ blksums) {
    __shared__ int sdata[SCAN_TPB];
    int base = blockIdx.x * SCAN_EPB + threadIdx.x * SCAN_EPT;
    int s = 0;
    #pragma unroll
    for (int k = 0; k < SCAN_EPT; ++k) {
        int idx = base + k;
        s += (idx < nc) ? counts[idx] : 0;
    }
    sdata[threadIdx.x] = s;
    __syncthreads();
    for (int off = SCAN_TPB / 2; off > 0; off >>= 1) {
        if (threadIdx.x < off) sdata[threadIdx.x] += sdata[threadIdx.x + off];
        __syncthreads();
    }
    if (threadIdx.x == 0) blksums[blockIdx.x] = sdata[0];
}

// K2: exclusive scan of block sums (nblk <= 512), write total sentinel
__global__ void scan_top_kernel(int* __restrict__ blksums, int nblk,
                                int* __restrict__ offsets, int nc) {
    __shared__ int sdata[512];
    int t = threadIdx.x;
    int v = (t < nblk) ? blksums[t] : 0;
    sdata[t] = v;
    __syncthreads();
    for (int off = 1; off < 512; off <<= 1) {
        int x = (t >= off) ? sdata[t - off] : 0;
        __syncthreads();
        sdata[t] += x;
        __syncthreads();
    }
    if (t < nblk) blksums[t] = sdata[t] - v;     // exclusive prefix
    if (t == 511) offsets[nc] = sdata[511];      // total = n1+n2 sentinel
}

// K3: local exclusive scan + block prefix -> offsets and cursor
__global__ void scan_write_kernel(const int* __restrict__ counts, int nc,
                                  const int* __restrict__ blksums,
                                  int* __restrict__ offsets, int* __restrict__ cursor) {
    __shared__ int sdata[SCAN_TPB];
    int t = threadIdx.x;
    int base = blockIdx.x * SCAN_EPB + t * SCAN_EPT;
    int local[SCAN_EPT];
    int s = 0;
    #pragma unroll
    for (int k = 0; k < SCAN_EPT; ++k) {
        int idx = base + k;
        int c = (idx < nc) ? counts[idx] : 0;
        local[k] = s;
        s += c;
    }
    sdata[t] = s;
    __syncthreads();
    for (int off = 1; off < SCAN_TPB; off <<= 1) {
        int x = (t >= off) ? sdata[t - off] : 0;
        __syncthreads();
        sdata[t] += x;
        __syncthreads();
    }
    int thread_excl = sdata[t] - s;
    int prefix = blksums[blockIdx.x] + thread_excl;
    #pragma unroll
    for (int k = 0; k < SCAN_EPT; ++k) {
        int idx = base + k;
        if (idx < nc) {
            int o = prefix + local[k];
            offsets[idx] = o;
            cursor[idx]  = o;
        }
    }
}

__global__ void place_kernel(const int* __restrict__ m1i, const int* __restrict__ m1o,
                             const int* __restrict__ m2i, const int* __restrict__ m2o,
                             int* __restrict__ cursor, int* __restrict__ idxpool,
                             int n1, int n2, int n_out) {
    int i = blockIdx.x * blockDim.x + threadIdx.x;
    int n = n1 + n2;
    if (i >= n) return;
    if (i < n1) {
        int pos = atomicAdd(&cursor[m1o[i]], 1);
        idxpool[pos] = m1i[i];
    } else {
        int j = i - n1;
        int pos = atomicAdd(&cursor[n_out + m2o[j]], 1);
        idxpool[pos] = m2i[j];
    }
}

// wave64 per output row: sum segment rows into registers, plain coalesced stores
__global__ void gather_kernel(const float* __restrict__ feat1,
                              const float* __restrict__ feat2,
                              const int* __restrict__ offsets,
                              const int* __restrict__ idxpool,
                              float* __restrict__ out, int n_out) {
    int gid  = blockIdx.x * blockDim.x + threadIdx.x;
    int r    = gid >> 6;
    int lane = gid & 63;
    if (r >= n_out) return;

    int s1b = offsets[r],         s1e = offsets[r + 1];
    int s2b = offsets[n_out + r], s2e = offsets[n_out + r + 1];

    float2 acc1 = {0.f, 0.f}, acc2 = {0.f, 0.f};
    for (int p = s1b; p < s1e; ++p) {
        int ir = idxpool[p];
        const float2 v = *reinterpret_cast<const float2*>(feat1 + (long)ir * C_IN + lane * 2);
        acc1.x += v.x; acc1.y += v.y;
    }
    for (int p = s2b; p < s2e; ++p) {
        int ir = idxpool[p];
        const float2 v = *reinterpret_cast<const float2*>(feat2 + (long)ir * C_IN + lane * 2);
        acc2.x += v.x; acc2.y += v.y;
    }

    float* dst = out + (long)r * C_OUT + lane * 2;
    *reinterpret_cast<float2*>(dst)        = acc1;
    *reinterpret_cast<float2*>(dst + C_IN) = acc2;
}

// ---------- fallback (R1 atomic path) if workspace is too small ----------
__global__ void zero_out_kernel(float4* __restrict__ out, long n4) {
    long i = (long)blockIdx.x * blockDim.x + threadIdx.x;
    long stride = (long)gridDim.x * blockDim.x;
    const float4 z = {0.f, 0.f, 0.f, 0.f};
    for (; i < n4; i += stride) out[i] = z;
}

__global__ void scatter_add_kernel(const float* __restrict__ feat,
                                   const int* __restrict__ map_in,
                                   const int* __restrict__ map_out,
                                   float* __restrict__ out,
                                   int n_rows, int col_off) {
    int gid = blockIdx.x * blockDim.x + threadIdx.x;
    int row = gid >> 6;
    int t   = gid & 63;
    if (row >= n_rows) return;
    int in_row  = map_in[row];
    int out_row = map_out[row];
    const float2 v = *reinterpret_cast<const float2*>(feat + (long)in_row * C_IN + t * 2);
    float* dst = out + (long)out_row * C_OUT + col_off + t * 2;
    unsafeAtomicAdd(dst,     v.x);
    unsafeAtomicAdd(dst + 1, v.y);
}

extern "C" void kernel_launch(void* const* d_in, const int* in_sizes, int n_in,
                              void* d_out, int out_size, void* d_ws, size_t ws_size,
                              hipStream_t stream) {
    const float* feat1    = (const float*)d_in[0];
    const float* feat2    = (const float*)d_in[1];
    const int*   map1_in  = (const int*)d_in[2];
    const int*   map1_out = (const int*)d_in[3];
    const int*   map2_in  = (const int*)d_in[4];
    const int*   map2_out = (const int*)d_in[5];
    float*       out      = (float*)d_out;

    const int n1    = in_sizes[0] / C_IN;      // 524288
    const int n2    = in_sizes[1] / C_IN;      // 524288
    const int n_out = out_size / C_OUT;        // 786432
    const int nc    = 2 * n_out;               // concatenated counters
    const int nblk  = (nc + SCAN_EPB - 1) / SCAN_EPB;   // 384

    // workspace carve
    size_t need = ((size_t)3 * nc + 1 + 512 + n1 + n2) * sizeof(int);
    if (ws_size >= need && nblk <= 512) {
        int* counts  = (int*)d_ws;
        int* offsets = counts + nc;             // nc+1 entries
        int* cursor  = offsets + nc + 1;
        int* blksums = cursor + nc;             // 512 entries
        int* idxpool = blksums + 512;

        zero_int_kernel<<<2048, 256, 0, stream>>>(counts, nc);

        int n = n1 + n2;
        count_kernel<<<(n + 255) / 256, 256, 0, stream>>>(
            map1_out, map2_out, counts, n1, n2, n_out);

        scan_blocksums_kernel<<<nblk, SCAN_TPB, 0, stream>>>(counts, nc, blksums);
        scan_top_kernel<<<1, 512, 0, stream>>>(blksums, nblk, offsets, nc);
        scan_write_kernel<<<nblk, SCAN_TPB, 0, stream>>>(counts, nc, blksums, offsets, cursor);

        place_kernel<<<(n + 255) / 256, 256, 0, stream>>>(
            map1_in, map1_out, map2_in, map2_out, cursor, idxpool, n1, n2, n_out);

        long threads_total = (long)n_out * 64;
        gather_kernel<<<(int)((threads_total + 255) / 256), 256, 0, stream>>>(
            feat1, feat2, offsets, idxpool, out, n_out);
    } else {
        // fallback: R1 atomic-scatter path
        long n4 = (long)out_size / 4;
        zero_out_kernel<<<2048, 256, 0, stream>>>((float4*)out, n4);
        scatter_add_kernel<<<(n1 + 3) / 4, 256, 0, stream>>>(
            feat1, map1_in, map1_out, out, n1, 0);
        scatter_add_kernel<<<(n2 + 3) / 4, 256, 0, stream>>>(
            feat2, map2_in, map2_out, out, n2, C_IN);
    }
}

// Round 4
// 475.406 us; speedup vs baseline: 2.1171x; 1.2263x over previous
//
#include <hip/hip_runtime.h>

// MinkowskiConcat forward, CSR-gather formulation (R4 = R3 with compile fix):
//   counts -> exclusive-scan offsets -> idxpool placement -> gather.
//   Gather: one wave per output row; lanes 0-31 reduce side1, lanes 32-63 side2,
//   float4 per lane; scalar segment-bound loads; non-temporal row stores.

constexpr int C_IN  = 128;
constexpr int C_OUT = 256;
constexpr int SCAN_TPB = 256;
constexpr int SCAN_EPT = 16;                      // elements per thread
constexpr int SCAN_EPB = SCAN_TPB * SCAN_EPT;     // 4096 per block

typedef float f32x4 __attribute__((ext_vector_type(4)));  // native vector: OK for nontemporal builtins

__global__ void count_kernel(const int* __restrict__ m1o, const int* __restrict__ m2o,
                             int* __restrict__ counts, int n1, int n2, int n_out) {
    int i = blockIdx.x * blockDim.x + threadIdx.x;
    int n = n1 + n2;
    if (i >= n) return;
    if (i < n1) atomicAdd(&counts[m1o[i]], 1);
    else        atomicAdd(&counts[n_out + m2o[i - n1]], 1);
}

// K1: per-block sums of counts
__global__ void scan_blocksums_kernel(const int* __restrict__ counts, int nc,
                                      int* __restrict__ blksums) {
    __shared__ int sdata[SCAN_TPB];
    int base = blockIdx.x * SCAN_EPB + threadIdx.x * SCAN_EPT;
    int s = 0;
    #pragma unroll
    for (int k = 0; k < SCAN_EPT; ++k) {
        int idx = base + k;
        s += (idx < nc) ? counts[idx] : 0;
    }
    sdata[threadIdx.x] = s;
    __syncthreads();
    for (int off = SCAN_TPB / 2; off > 0; off >>= 1) {
        if (threadIdx.x < off) sdata[threadIdx.x] += sdata[threadIdx.x + off];
        __syncthreads();
    }
    if (threadIdx.x == 0) blksums[blockIdx.x] = sdata[0];
}

// K2: exclusive scan of block sums (nblk <= 512), write total sentinel
__global__ void scan_top_kernel(int* __restrict__ blksums, int nblk,
                                int* __restrict__ offsets, int nc) {
    __shared__ int sdata[512];
    int t = threadIdx.x;
    int v = (t < nblk) ? blksums[t] : 0;
    sdata[t] = v;
    __syncthreads();
    for (int off = 1; off < 512; off <<= 1) {
        int x = (t >= off) ? sdata[t - off] : 0;
        __syncthreads();
        sdata[t] += x;
        __syncthreads();
    }
    if (t < nblk) blksums[t] = sdata[t] - v;     // exclusive prefix
    if (t == 511) offsets[nc] = sdata[511];      // total = n1+n2 sentinel
}

// K3: local exclusive scan + block prefix -> offsets and cursor
__global__ void scan_write_kernel(const int* __restrict__ counts, int nc,
                                  const int* __restrict__ blksums,
                                  int* __restrict__ offsets, int* __restrict__ cursor) {
    __shared__ int sdata[SCAN_TPB];
    int t = threadIdx.x;
    int base = blockIdx.x * SCAN_EPB + t * SCAN_EPT;
    int local[SCAN_EPT];
    int s = 0;
    #pragma unroll
    for (int k = 0; k < SCAN_EPT; ++k) {
        int idx = base + k;
        int c = (idx < nc) ? counts[idx] : 0;
        local[k] = s;
        s += c;
    }
    sdata[t] = s;
    __syncthreads();
    for (int off = 1; off < SCAN_TPB; off <<= 1) {
        int x = (t >= off) ? sdata[t - off] : 0;
        __syncthreads();
        sdata[t] += x;
        __syncthreads();
    }
    int thread_excl = sdata[t] - s;
    int prefix = blksums[blockIdx.x] + thread_excl;
    #pragma unroll
    for (int k = 0; k < SCAN_EPT; ++k) {
        int idx = base + k;
        if (idx < nc) {
            int o = prefix + local[k];
            offsets[idx] = o;
            cursor[idx]  = o;
        }
    }
}

__global__ void place_kernel(const int* __restrict__ m1i, const int* __restrict__ m1o,
                             const int* __restrict__ m2i, const int* __restrict__ m2o,
                             int* __restrict__ cursor, int* __restrict__ idxpool,
                             int n1, int n2, int n_out) {
    int i = blockIdx.x * blockDim.x + threadIdx.x;
    int n = n1 + n2;
    if (i >= n) return;
    if (i < n1) {
        int pos = atomicAdd(&cursor[m1o[i]], 1);
        idxpool[pos] = m1i[i];
    } else {
        int j = i - n1;
        int pos = atomicAdd(&cursor[n_out + m2o[j]], 1);
        idxpool[pos] = m2i[j];
    }
}

// One wave per output row. Lanes 0-31: side1 (cols 0-127, float4/lane);
// lanes 32-63: side2 (cols 128-255). Segment bounds via scalar loads.
__global__ void gather_kernel(const float* __restrict__ feat1,
                              const float* __restrict__ feat2,
                              const int* __restrict__ offsets,
                              const int* __restrict__ idxpool,
                              float* __restrict__ out, int n_out) {
    int gid  = blockIdx.x * blockDim.x + threadIdx.x;
    int r    = __builtin_amdgcn_readfirstlane(gid >> 6);   // wave-uniform row
    if (r >= n_out) return;
    int lane = threadIdx.x & 63;
    int side = lane >> 5;
    int l    = lane & 31;

    // wave-uniform segment bounds -> s_load
    int b1 = offsets[r];
    int e1 = offsets[r + 1];
    int b2 = offsets[n_out + r];
    int e2 = offsets[n_out + r + 1];

    int b = side ? b2 : b1;
    int e = side ? e2 : e1;
    const float* feat = side ? feat2 : feat1;

    f32x4 acc = {0.f, 0.f, 0.f, 0.f};
    for (int p = b; p < e; ++p) {
        int ir = idxpool[p];
        const f32x4 v =
            *reinterpret_cast<const f32x4*>(feat + (long)ir * C_IN + l * 4);
        acc += v;
    }

    // non-temporal full-row store: keep 805 MB write stream out of L2/L3
    f32x4* dst = reinterpret_cast<f32x4*>(out + (long)r * C_OUT + side * C_IN + l * 4);
    __builtin_nontemporal_store(acc, dst);
}

// ---------- fallback (R1 atomic path) if workspace is too small ----------
__global__ void zero_out_kernel(float4* __restrict__ out, long n4) {
    long i = (long)blockIdx.x * blockDim.x + threadIdx.x;
    long stride = (long)gridDim.x * blockDim.x;
    const float4 z = {0.f, 0.f, 0.f, 0.f};
    for (; i < n4; i += stride) out[i] = z;
}

__global__ void scatter_add_kernel(const float* __restrict__ feat,
                                   const int* __restrict__ map_in,
                                   const int* __restrict__ map_out,
                                   float* __restrict__ out,
                                   int n_rows, int col_off) {
    int gid = blockIdx.x * blockDim.x + threadIdx.x;
    int row = gid >> 6;
    int t   = gid & 63;
    if (row >= n_rows) return;
    int in_row  = map_in[row];
    int out_row = map_out[row];
    const float2 v = *reinterpret_cast<const float2*>(feat + (long)in_row * C_IN + t * 2);
    float* dst = out + (long)out_row * C_OUT + col_off + t * 2;
    unsafeAtomicAdd(dst,     v.x);
    unsafeAtomicAdd(dst + 1, v.y);
}

extern "C" void kernel_launch(void* const* d_in, const int* in_sizes, int n_in,
                              void* d_out, int out_size, void* d_ws, size_t ws_size,
                              hipStream_t stream) {
    const float* feat1    = (const float*)d_in[0];
    const float* feat2    = (const float*)d_in[1];
    const int*   map1_in  = (const int*)d_in[2];
    const int*   map1_out = (const int*)d_in[3];
    const int*   map2_in  = (const int*)d_in[4];
    const int*   map2_out = (const int*)d_in[5];
    float*       out      = (float*)d_out;

    const int n1    = in_sizes[0] / C_IN;      // 524288
    const int n2    = in_sizes[1] / C_IN;      // 524288
    const int n_out = out_size / C_OUT;        // 786432
    const int nc    = 2 * n_out;               // concatenated counters
    const int nblk  = (nc + SCAN_EPB - 1) / SCAN_EPB;   // 384

    size_t need = ((size_t)3 * nc + 1 + 512 + n1 + n2) * sizeof(int);
    if (ws_size >= need && nblk <= 512) {
        int* counts  = (int*)d_ws;
        int* offsets = counts + nc;             // nc+1 entries
        int* cursor  = offsets + nc + 1;
        int* blksums = cursor + nc;             // 512 entries
        int* idxpool = blksums + 512;

        (void)hipMemsetAsync(counts, 0, (size_t)nc * sizeof(int), stream);

        int n = n1 + n2;
        count_kernel<<<(n + 255) / 256, 256, 0, stream>>>(
            map1_out, map2_out, counts, n1, n2, n_out);

        scan_blocksums_kernel<<<nblk, SCAN_TPB, 0, stream>>>(counts, nc, blksums);
        scan_top_kernel<<<1, 512, 0, stream>>>(blksums, nblk, offsets, nc);
        scan_write_kernel<<<nblk, SCAN_TPB, 0, stream>>>(counts, nc, blksums, offsets, cursor);

        place_kernel<<<(n + 255) / 256, 256, 0, stream>>>(
            map1_in, map1_out, map2_in, map2_out, cursor, idxpool, n1, n2, n_out);

        long threads_total = (long)n_out * 64;
        gather_kernel<<<(int)((threads_total + 255) / 256), 256, 0, stream>>>(
            feat1, feat2, offsets, idxpool, out, n_out);
    } else {
        long n4 = (long)out_size / 4;
        zero_out_kernel<<<2048, 256, 0, stream>>>((float4*)out, n4);
        scatter_add_kernel<<<(n1 + 3) / 4, 256, 0, stream>>>(
            feat1, map1_in, map1_out, out, n1, 0);
        scatter_add_kernel<<<(n2 + 3) / 4, 256, 0, stream>>>(
            feat2, map2_in, map2_out, out, n2, C_IN);
    }
}

// Round 5
// 396.922 us; speedup vs baseline: 2.5357x; 1.1977x over previous
//
#include <hip/hip_runtime.h>

// MinkowskiConcat forward, CSR-gather (R5):
//   counts -> exclusive-scan offsets -> idxpool placement -> gather.
//   Gather v2: one wave handles FOUR output rows (lanes 0-31 side1, 32-63 side2,
//   float4/lane). Phase-split so the 4 indirection chains (idxpool -> feat)
//   overlap -> 4x memory-level parallelism. Non-temporal row stores.

constexpr int C_IN  = 128;
constexpr int C_OUT = 256;
constexpr int SCAN_TPB = 256;
constexpr int SCAN_EPT = 16;
constexpr int SCAN_EPB = SCAN_TPB * SCAN_EPT;     // 4096 per block
constexpr int RPW = 4;                            // rows per wave in gather

typedef float f32x4 __attribute__((ext_vector_type(4)));

__global__ void count_kernel(const int* __restrict__ m1o, const int* __restrict__ m2o,
                             int* __restrict__ counts, int n1, int n2, int n_out) {
    int i = blockIdx.x * blockDim.x + threadIdx.x;
    int n = n1 + n2;
    if (i >= n) return;
    if (i < n1) atomicAdd(&counts[m1o[i]], 1);
    else        atomicAdd(&counts[n_out + m2o[i - n1]], 1);
}

__global__ void scan_blocksums_kernel(const int* __restrict__ counts, int nc,
                                      int* __restrict__ blksums) {
    __shared__ int sdata[SCAN_TPB];
    int base = blockIdx.x * SCAN_EPB + threadIdx.x * SCAN_EPT;
    int s = 0;
    #pragma unroll
    for (int k = 0; k < SCAN_EPT; ++k) {
        int idx = base + k;
        s += (idx < nc) ? counts[idx] : 0;
    }
    sdata[threadIdx.x] = s;
    __syncthreads();
    for (int off = SCAN_TPB / 2; off > 0; off >>= 1) {
        if (threadIdx.x < off) sdata[threadIdx.x] += sdata[threadIdx.x + off];
        __syncthreads();
    }
    if (threadIdx.x == 0) blksums[blockIdx.x] = sdata[0];
}

__global__ void scan_top_kernel(int* __restrict__ blksums, int nblk,
                                int* __restrict__ offsets, int nc) {
    __shared__ int sdata[512];
    int t = threadIdx.x;
    int v = (t < nblk) ? blksums[t] : 0;
    sdata[t] = v;
    __syncthreads();
    for (int off = 1; off < 512; off <<= 1) {
        int x = (t >= off) ? sdata[t - off] : 0;
        __syncthreads();
        sdata[t] += x;
        __syncthreads();
    }
    if (t < nblk) blksums[t] = sdata[t] - v;
    if (t == 511) offsets[nc] = sdata[511];
}

__global__ void scan_write_kernel(const int* __restrict__ counts, int nc,
                                  const int* __restrict__ blksums,
                                  int* __restrict__ offsets, int* __restrict__ cursor) {
    __shared__ int sdata[SCAN_TPB];
    int t = threadIdx.x;
    int base = blockIdx.x * SCAN_EPB + t * SCAN_EPT;
    int local[SCAN_EPT];
    int s = 0;
    #pragma unroll
    for (int k = 0; k < SCAN_EPT; ++k) {
        int idx = base + k;
        int c = (idx < nc) ? counts[idx] : 0;
        local[k] = s;
        s += c;
    }
    sdata[t] = s;
    __syncthreads();
    for (int off = 1; off < SCAN_TPB; off <<= 1) {
        int x = (t >= off) ? sdata[t - off] : 0;
        __syncthreads();
        sdata[t] += x;
        __syncthreads();
    }
    int thread_excl = sdata[t] - s;
    int prefix = blksums[blockIdx.x] + thread_excl;
    #pragma unroll
    for (int k = 0; k < SCAN_EPT; ++k) {
        int idx = base + k;
        if (idx < nc) {
            int o = prefix + local[k];
            offsets[idx] = o;
            cursor[idx]  = o;
        }
    }
}

__global__ void place_kernel(const int* __restrict__ m1i, const int* __restrict__ m1o,
                             const int* __restrict__ m2i, const int* __restrict__ m2o,
                             int* __restrict__ cursor, int* __restrict__ idxpool,
                             int n1, int n2, int n_out) {
    int i = blockIdx.x * blockDim.x + threadIdx.x;
    int n = n1 + n2;
    if (i >= n) return;
    if (i < n1) {
        int pos = atomicAdd(&cursor[m1o[i]], 1);
        idxpool[pos] = m1i[i];
    } else {
        int j = i - n1;
        int pos = atomicAdd(&cursor[n_out + m2o[j]], 1);
        idxpool[pos] = m2i[j];
    }
}

// Gather v2: one wave per RPW output rows; lanes 0-31 side1, 32-63 side2.
// Phase-split to overlap the 4 independent idxpool->feat chains.
__global__ void gather_kernel(const float* __restrict__ feat1,
                              const float* __restrict__ feat2,
                              const int* __restrict__ offsets,
                              const int* __restrict__ idxpool,
                              float* __restrict__ out, int n_out) {
    int wid  = (blockIdx.x * blockDim.x + threadIdx.x) >> 6;
    int lane = threadIdx.x & 63;
    int side = lane >> 5;
    int l    = lane & 31;
    int r0   = wid * RPW;
    if (r0 >= n_out) return;

    const float* feat = side ? feat2 : feat1;
    const int obase   = side ? n_out : 0;

    // segment bounds for RPW consecutive rows (per half-wave uniform)
    int b[RPW], e[RPW];
    #pragma unroll
    for (int k = 0; k < RPW; ++k) {
        int r  = r0 + k;
        bool ok = (r < n_out);
        b[k] = ok ? offsets[obase + r]     : 0;
        e[k] = ok ? offsets[obase + r + 1] : 0;
    }

    // phase 1: first-element pool indices — 4 independent loads in flight
    int i0[RPW];
    #pragma unroll
    for (int k = 0; k < RPW; ++k)
        i0[k] = (b[k] < e[k]) ? idxpool[b[k]] : -1;

    // phase 2: first feat-row loads — 4 chains pipeline
    f32x4 acc[RPW];
    #pragma unroll
    for (int k = 0; k < RPW; ++k) {
        f32x4 v = {0.f, 0.f, 0.f, 0.f};
        if (i0[k] >= 0)
            v = *reinterpret_cast<const f32x4*>(feat + (long)i0[k] * C_IN + l * 4);
        acc[k] = v;
    }

    // phase 3: rare tails (count >= 2; ~14% of nonempty segments)
    #pragma unroll
    for (int k = 0; k < RPW; ++k) {
        for (int p = b[k] + 1; p < e[k]; ++p) {
            int ir = idxpool[p];
            acc[k] += *reinterpret_cast<const f32x4*>(feat + (long)ir * C_IN + l * 4);
        }
    }

    // phase 4: non-temporal full-row stores
    #pragma unroll
    for (int k = 0; k < RPW; ++k) {
        int r = r0 + k;
        if (r < n_out) {
            f32x4* dst = reinterpret_cast<f32x4*>(out + (long)r * C_OUT + side * C_IN + l * 4);
            __builtin_nontemporal_store(acc[k], dst);
        }
    }
}

// ---------- fallback (R1 atomic path) if workspace is too small ----------
__global__ void zero_out_kernel(float4* __restrict__ out, long n4) {
    long i = (long)blockIdx.x * blockDim.x + threadIdx.x;
    long stride = (long)gridDim.x * blockDim.x;
    const float4 z = {0.f, 0.f, 0.f, 0.f};
    for (; i < n4; i += stride) out[i] = z;
}

__global__ void scatter_add_kernel(const float* __restrict__ feat,
                                   const int* __restrict__ map_in,
                                   const int* __restrict__ map_out,
                                   float* __restrict__ out,
                                   int n_rows, int col_off) {
    int gid = blockIdx.x * blockDim.x + threadIdx.x;
    int row = gid >> 6;
    int t   = gid & 63;
    if (row >= n_rows) return;
    int in_row  = map_in[row];
    int out_row = map_out[row];
    const float2 v = *reinterpret_cast<const float2*>(feat + (long)in_row * C_IN + t * 2);
    float* dst = out + (long)out_row * C_OUT + col_off + t * 2;
    unsafeAtomicAdd(dst,     v.x);
    unsafeAtomicAdd(dst + 1, v.y);
}

extern "C" void kernel_launch(void* const* d_in, const int* in_sizes, int n_in,
                              void* d_out, int out_size, void* d_ws, size_t ws_size,
                              hipStream_t stream) {
    const float* feat1    = (const float*)d_in[0];
    const float* feat2    = (const float*)d_in[1];
    const int*   map1_in  = (const int*)d_in[2];
    const int*   map1_out = (const int*)d_in[3];
    const int*   map2_in  = (const int*)d_in[4];
    const int*   map2_out = (const int*)d_in[5];
    float*       out      = (float*)d_out;

    const int n1    = in_sizes[0] / C_IN;      // 524288
    const int n2    = in_sizes[1] / C_IN;      // 524288
    const int n_out = out_size / C_OUT;        // 786432
    const int nc    = 2 * n_out;
    const int nblk  = (nc + SCAN_EPB - 1) / SCAN_EPB;   // 384

    size_t need = ((size_t)3 * nc + 1 + 512 + n1 + n2) * sizeof(int);
    if (ws_size >= need && nblk <= 512) {
        int* counts  = (int*)d_ws;
        int* offsets = counts + nc;             // nc+1 entries
        int* cursor  = offsets + nc + 1;
        int* blksums = cursor + nc;             // 512 entries
        int* idxpool = blksums + 512;

        (void)hipMemsetAsync(counts, 0, (size_t)nc * sizeof(int), stream);

        int n = n1 + n2;
        count_kernel<<<(n + 255) / 256, 256, 0, stream>>>(
            map1_out, map2_out, counts, n1, n2, n_out);

        scan_blocksums_kernel<<<nblk, SCAN_TPB, 0, stream>>>(counts, nc, blksums);
        scan_top_kernel<<<1, 512, 0, stream>>>(blksums, nblk, offsets, nc);
        scan_write_kernel<<<nblk, SCAN_TPB, 0, stream>>>(counts, nc, blksums, offsets, cursor);

        place_kernel<<<(n + 255) / 256, 256, 0, stream>>>(
            map1_in, map1_out, map2_in, map2_out, cursor, idxpool, n1, n2, n_out);

        // one wave per RPW rows
        long waves   = ((long)n_out + RPW - 1) / RPW;
        long threads = waves * 64;
        gather_kernel<<<(int)((threads + 255) / 256), 256, 0, stream>>>(
            feat1, feat2, offsets, idxpool, out, n_out);
    } else {
        long n4 = (long)out_size / 4;
        zero_out_kernel<<<2048, 256, 0, stream>>>((float4*)out, n4);
        scatter_add_kernel<<<(n1 + 3) / 4, 256, 0, stream>>>(
            feat1, map1_in, map1_out, out, n1, 0);
        scatter_add_kernel<<<(n2 + 3) / 4, 256, 0, stream>>>(
            feat2, map2_in, map2_out, out, n2, C_IN);
    }
}